// Round 1
// baseline (1790.151 us; speedup 1.0000x reference)
//
#include <hip/hip_runtime.h>
#include <hip/hip_bf16.h>
#include <stdint.h>

#define L_ 2048
#define S_ 2048
#define D_ 64

typedef float f32x4 __attribute__((ext_vector_type(4)));
typedef __bf16 bf16x8 __attribute__((ext_vector_type(8)));

__device__ __forceinline__ unsigned short f2b(float x) {
    return __builtin_bit_cast(unsigned short, (__bf16)x);
}
__device__ __forceinline__ float h2f(unsigned short u) {
    return (float)__builtin_bit_cast(_Float16, u);
}

// ============ prep 1: K fp32 -> K2 bf16 in per-(ci,lane) frag order ========
// K2 flat 16B units: t = ((((bh*8+it)*8+w)*2+nt)*2+ks)*64 + lan
// value e of unit = K[bh][s = it*256+w*32+nt*16+li][d = ks*32+g*8+e]
// (flat chunk index ci = it*8+w; main kernel re-slices ci as it16*4+w4)
__global__ void convk2_kernel(const float* __restrict__ k, unsigned short* __restrict__ k2) {
    const int t = blockIdx.x * 256 + threadIdx.x;       // 1,048,576 total
    const int lan = t & 63, ks = (t >> 6) & 1, nt = (t >> 7) & 1;
    const int w = (t >> 8) & 7, it = (t >> 11) & 7, bh = t >> 14;
    const int li = lan & 15, g = lan >> 4;
    const int s  = it * 256 + w * 32 + nt * 16 + li;
    const int d0 = ks * 32 + g * 8;
    const float* src = k + ((size_t)bh * S_ + s) * D_ + d0;
    float4 a = *(const float4*)src;
    float4 b = *(const float4*)(src + 4);
    uint4 o;
    o.x = (unsigned)f2b(a.x) | ((unsigned)f2b(a.y) << 16);
    o.y = (unsigned)f2b(a.z) | ((unsigned)f2b(a.w) << 16);
    o.z = (unsigned)f2b(b.x) | ((unsigned)f2b(b.y) << 16);
    o.w = (unsigned)f2b(b.z) | ((unsigned)f2b(b.w) << 16);
    *(uint4*)(k2 + (size_t)t * 8) = o;
}

// ============ prep 2: V fp32 -> V2 bf16 frag order =========================
// V2 16B units: t = ((((bh*8+it)*8+w)*4+dt)*64) + lan
// value e = V[bh][s = it*256+w*32+g*8+e][d = dt*16+li]
__global__ void convv2_kernel(const float* __restrict__ v, unsigned short* __restrict__ v2) {
    const int t = blockIdx.x * 256 + threadIdx.x;       // 1,048,576 total
    const int lan = t & 63, dt = (t >> 6) & 3;
    const int w = (t >> 8) & 7, it = (t >> 11) & 7, bh = t >> 14;
    const int li = lan & 15, g = lan >> 4;
    const int s0 = it * 256 + w * 32 + g * 8;
    const int d  = dt * 16 + li;
    unsigned short o[8];
    #pragma unroll
    for (int e = 0; e < 8; ++e)
        o[e] = f2b(v[((size_t)bh * S_ + s0 + e) * D_ + d]);
    uint4 u;
    u.x = (unsigned)o[0] | ((unsigned)o[1] << 16);
    u.y = (unsigned)o[2] | ((unsigned)o[3] << 16);
    u.z = (unsigned)o[4] | ((unsigned)o[5] << 16);
    u.w = (unsigned)o[6] | ((unsigned)o[7] << 16);
    *(uint4*)(v2 + (size_t)t * 8) = u;
}

// ============ prep 3: bias+mask -> mb2 f16 in per-(ci,thread) order ========
// mb2 16B units: t = (((b*128+lt)*8+it)*512) + tid512
// val[nt*4+j] = masked ? -60000 : bias[b][lt*16+g*4+j][it*256+w*32+nt*16+li]
__global__ void fusemb2_kernel(const float* __restrict__ bias, const void* __restrict__ maskp,
                               unsigned short* __restrict__ mb2) {
    const unsigned* mw = (const unsigned*)maskp;
    int is4 = 1;
    for (int i = 0; i < 64; ++i) {
        unsigned wv = mw[i];
        if (!(wv == 0u || wv == 1u || wv == 0x3F800000u)) { is4 = 0; break; }
    }
    const int t = blockIdx.x * 256 + threadIdx.x;       // 2,097,152 total
    const int tid = t & 511, it = (t >> 9) & 7, lt = (t >> 12) & 127, b = t >> 19;
    const int w = tid >> 6, lan = tid & 63, g = lan >> 4, li = lan & 15;
    const unsigned short NEG = __builtin_bit_cast(unsigned short, (_Float16)(-60000.0f));
    const int* maski = (const int*)maskp;
    const unsigned char* maskb = (const unsigned char*)maskp;
    unsigned short o[8];
    #pragma unroll
    for (int nt = 0; nt < 2; ++nt)
      #pragma unroll
      for (int j = 0; j < 4; ++j) {
          size_t idx = ((size_t)b * L_ + lt * 16 + g * 4 + j) * S_
                     + it * 256 + w * 32 + nt * 16 + li;
          int m = is4 ? (maski[idx] != 0) : (maskb[idx] != 0);
          o[nt * 4 + j] = m ? NEG
                            : __builtin_bit_cast(unsigned short, (_Float16)bias[idx]);
      }
    uint4 u;
    u.x = (unsigned)o[0] | ((unsigned)o[1] << 16);
    u.y = (unsigned)o[2] | ((unsigned)o[3] << 16);
    u.z = (unsigned)o[4] | ((unsigned)o[5] << 16);
    u.w = (unsigned)o[6] | ((unsigned)o[7] << 16);
    *(uint4*)(mb2 + (size_t)t * 8) = u;
}

// ============ main fused attention: two-pass, C=0 softmax ==================
// 8192 WGs = (b, 16 heads, 128 l-tiles of 16 rows), 256 thr (4 waves).
// Scores are bounded: s = 0.125*qk + bias in ~[-12,12]; masked -> -6e4
// (exp == 0 exactly). So softmax needs NO max subtraction: pass A streams
// K2+mb2 and accumulates only l = sum(exp(s)) -- no 64-reg score array.
// Pass B re-streams K2+mb2 (bit-identical MFMA -> identical s), computes
// p = exp(s)/l, stores attn, and accumulates PV. Register pressure drops
// from ~128 (unified, 4 waves/SIMD) to ~73 -> 7 waves/SIMD, and each CU
// pipelines ~32 short blocks through ~7 slots: many independent convoys.
// Only 4 barriers per WG total (2 sum-reduce + 2 out-reduce).
__launch_bounds__(256, 7)
__global__ void attn_main_kernel(const float* __restrict__ q,
                                 const unsigned short* __restrict__ mb2,
                                 const unsigned short* __restrict__ k2,
                                 const unsigned short* __restrict__ v2,
                                 float* __restrict__ outp,
                                 float* __restrict__ attnp)
{
    __shared__ __align__(16) char lds[16384];
    float* outred = (float*)lds;                 // [4][16][64] f32 (post-PV)
    float* redbuf = (float*)(lds + 5120);        // [4][16] row partial sums
    float* rowred = (float*)(lds + 5376);        // [16] 1/l
    const int tid = threadIdx.x;
    const int w = tid >> 6, lan = tid & 63, g = lan >> 4, li = lan & 15;
    char* pbuf = lds + w * 1280;                 // per-wave P tile [16][80B]

    // bijective XCD chunking: XCD x gets c in [x*1024, x*1024+1024) with
    // c = ((b*2+lthi)*16 + h)*64 + ltlo. Heads sweep sequentially per XCD
    // (only ~2 heads' K2/V2 = ~1MB hot at a time) while the XCD's 64 mb2
    // lt-slices (4MB) stay L2-resident across all 16 h x 2 passes.
    const int c   = ((blockIdx.x & 7) << 10) | (blockIdx.x >> 3);
    const int xcd = c >> 10;
    const int h   = (c >> 6) & 15;
    const int b   = xcd >> 1;
    const int lt  = ((xcd & 1) << 6) | (c & 63);
    const int l0  = lt * 16;
    const int bh  = (b << 4) | h;

    const unsigned short* mbbase = mb2 + (size_t)(b * 128 + lt) * 32768
                                 + w * 512 + (size_t)lan * 8;
    const unsigned short* kbase  = k2 + (size_t)bh * 131072 + w * 2048 + (size_t)lan * 8;
    const unsigned short* vbase  = v2 + (size_t)bh * 131072 + w * 2048 + (size_t)lan * 8;
    const f32x4 vzero = {0.f, 0.f, 0.f, 0.f};

    // ---- Q fragments (held in regs across both passes) ----
    bf16x8 qf[2];
    #pragma unroll
    for (int ks = 0; ks < 2; ++ks) {
        const float* qp = q + ((size_t)bh * L_ + (l0 + li)) * D_ + ks * 32 + g * 8;
        float4 xv = *(const float4*)qp;
        float4 yv = *(const float4*)(qp + 4);
        bf16x8 f;
        f[0]=(__bf16)xv.x; f[1]=(__bf16)xv.y; f[2]=(__bf16)xv.z; f[3]=(__bf16)xv.w;
        f[4]=(__bf16)yv.x; f[5]=(__bf16)yv.y; f[6]=(__bf16)yv.z; f[7]=(__bf16)yv.w;
        qf[ks] = f;
    }

    // ================= pass A: l[row] = sum_s exp(s) (barrier-free) ========
    float l4[4] = {0.f, 0.f, 0.f, 0.f};
    #pragma unroll
    for (int it = 0; it < 16; ++it) {
        const unsigned short* kit = kbase + it * 8192;
        uint4 f00 = *(const uint4*)(kit);            // nt0 ks0
        uint4 f01 = *(const uint4*)(kit + 512);      // nt0 ks1
        uint4 f10 = *(const uint4*)(kit + 1024);     // nt1 ks0
        uint4 f11 = *(const uint4*)(kit + 1536);     // nt1 ks1
        uint4 mp  = *(const uint4*)(mbbase + it * 2048);
        f32x4 a0 = vzero, a1 = vzero;
        a0 = __builtin_amdgcn_mfma_f32_16x16x32_bf16(
            qf[0], __builtin_bit_cast(bf16x8, f00), a0, 0, 0, 0);
        a0 = __builtin_amdgcn_mfma_f32_16x16x32_bf16(
            qf[1], __builtin_bit_cast(bf16x8, f01), a0, 0, 0, 0);
        a1 = __builtin_amdgcn_mfma_f32_16x16x32_bf16(
            qf[0], __builtin_bit_cast(bf16x8, f10), a1, 0, 0, 0);
        a1 = __builtin_amdgcn_mfma_f32_16x16x32_bf16(
            qf[1], __builtin_bit_cast(bf16x8, f11), a1, 0, 0, 0);
        float mbv[2][4];
        mbv[0][0] = h2f((unsigned short)(mp.x & 0xffff));
        mbv[0][1] = h2f((unsigned short)(mp.x >> 16));
        mbv[0][2] = h2f((unsigned short)(mp.y & 0xffff));
        mbv[0][3] = h2f((unsigned short)(mp.y >> 16));
        mbv[1][0] = h2f((unsigned short)(mp.z & 0xffff));
        mbv[1][1] = h2f((unsigned short)(mp.z >> 16));
        mbv[1][2] = h2f((unsigned short)(mp.w & 0xffff));
        mbv[1][3] = h2f((unsigned short)(mp.w >> 16));
        #pragma unroll
        for (int j = 0; j < 4; ++j) {
            float e0 = __expf(fmaf(a0[j], 0.125f, mbv[0][j]));
            float e1 = __expf(fmaf(a1[j], 0.125f, mbv[1][j]));
            l4[j] += e0 + e1;
        }
    }
    // reduce over 16 li lanes (shfl), then across 4 waves (2 barriers)
    #pragma unroll
    for (int j = 0; j < 4; ++j) {
        float s = l4[j];
        s += __shfl_xor(s, 1);
        s += __shfl_xor(s, 2);
        s += __shfl_xor(s, 4);
        s += __shfl_xor(s, 8);
        l4[j] = s;
    }
    if (li == 0) {
        #pragma unroll
        for (int j = 0; j < 4; ++j) redbuf[w * 16 + g * 4 + j] = l4[j];
    }
    __syncthreads();
    if (tid < 16) {
        float s = redbuf[tid] + redbuf[16 + tid] + redbuf[32 + tid] + redbuf[48 + tid];
        rowred[tid] = 1.0f / s;
    }
    __syncthreads();
    float rinv[4];
    #pragma unroll
    for (int j = 0; j < 4; ++j) rinv[j] = rowred[g * 4 + j];

    // ========== pass B: recompute s, store attn, PV (barrier-free) =========
    f32x4 oacc[4];
    #pragma unroll
    for (int dt = 0; dt < 4; ++dt) oacc[dt] = vzero;
    float* attnw = attnp + (size_t)bh * ((size_t)L_ * S_) + (size_t)l0 * S_;

    #pragma unroll
    for (int it = 0; it < 16; ++it) {
        const unsigned short* kit = kbase + it * 8192;
        const unsigned short* vit = vbase + it * 8192;
        uint4 f00 = *(const uint4*)(kit);
        uint4 f01 = *(const uint4*)(kit + 512);
        uint4 f10 = *(const uint4*)(kit + 1024);
        uint4 f11 = *(const uint4*)(kit + 1536);
        uint4 mp  = *(const uint4*)(mbbase + it * 2048);
        f32x4 a0 = vzero, a1 = vzero;
        a0 = __builtin_amdgcn_mfma_f32_16x16x32_bf16(
            qf[0], __builtin_bit_cast(bf16x8, f00), a0, 0, 0, 0);
        a0 = __builtin_amdgcn_mfma_f32_16x16x32_bf16(
            qf[1], __builtin_bit_cast(bf16x8, f01), a0, 0, 0, 0);
        a1 = __builtin_amdgcn_mfma_f32_16x16x32_bf16(
            qf[0], __builtin_bit_cast(bf16x8, f10), a1, 0, 0, 0);
        a1 = __builtin_amdgcn_mfma_f32_16x16x32_bf16(
            qf[1], __builtin_bit_cast(bf16x8, f11), a1, 0, 0, 0);
        float mbv[2][4];
        mbv[0][0] = h2f((unsigned short)(mp.x & 0xffff));
        mbv[0][1] = h2f((unsigned short)(mp.x >> 16));
        mbv[0][2] = h2f((unsigned short)(mp.y & 0xffff));
        mbv[0][3] = h2f((unsigned short)(mp.y >> 16));
        mbv[1][0] = h2f((unsigned short)(mp.z & 0xffff));
        mbv[1][1] = h2f((unsigned short)(mp.z >> 16));
        mbv[1][2] = h2f((unsigned short)(mp.w & 0xffff));
        mbv[1][3] = h2f((unsigned short)(mp.w >> 16));
        float a[2][4];
        #pragma unroll
        for (int j = 0; j < 4; ++j) {
            a[0][j] = __expf(fmaf(a0[j], 0.125f, mbv[0][j])) * rinv[j];
            a[1][j] = __expf(fmaf(a1[j], 0.125f, mbv[1][j])) * rinv[j];
        }
        // nontemporal attn stores; j-outer/nt-inner pairs 128B lines
        #pragma unroll
        for (int j = 0; j < 4; ++j)
          #pragma unroll
          for (int nt = 0; nt < 2; ++nt)
              __builtin_nontemporal_store(a[nt][j],
                  attnw + (size_t)(g * 4 + j) * S_ + it * 128 + w * 32 + nt * 16 + li);
        // P -> per-wave LDS (wave-local transpose bounce; same-wave ds
        // ordering via lgkmcnt, no barrier)
        #pragma unroll
        for (int nt = 0; nt < 2; ++nt)
          #pragma unroll
          for (int j = 0; j < 4; ++j)
              *(unsigned short*)(pbuf + (g * 4 + j) * 80 + (nt * 16 + li) * 2)
                  = f2b(a[nt][j]);
        bf16x8 pf = *(const bf16x8*)(pbuf + li * 80 + g * 16);
        #pragma unroll
        for (int dt = 0; dt < 4; ++dt) {
            uint4 vd = *(const uint4*)(vit + dt * 512);
            oacc[dt] = __builtin_amdgcn_mfma_f32_16x16x32_bf16(
                pf, __builtin_bit_cast(bf16x8, vd), oacc[dt], 0, 0, 0);
        }
    }

    // ================= cross-wave out reduction (2 barriers) ===============
    __syncthreads();                             // PV done (pbuf -> outred reuse)
    #pragma unroll
    for (int dt = 0; dt < 4; ++dt)
      #pragma unroll
      for (int j = 0; j < 4; ++j)
          outred[(w * 16 + g * 4 + j) * 64 + dt * 16 + li] = oacc[dt][j];
    __syncthreads();
    {
        int r = tid >> 4, c4 = (tid & 15) << 2;
        f32x4 ssum = *(const f32x4*)(outred + r * 64 + c4);
        #pragma unroll
        for (int ww = 1; ww < 4; ++ww)
            ssum += *(const f32x4*)(outred + (ww * 16 + r) * 64 + c4);
        __builtin_nontemporal_store(ssum,
            (f32x4*)(outp + ((size_t)bh * L_ + (l0 + r)) * D_ + c4));
    }
}

extern "C" void kernel_launch(void* const* d_in, const int* in_sizes, int n_in,
                              void* d_out, int out_size, void* d_ws, size_t ws_size,
                              hipStream_t stream) {
    const float* q    = (const float*)d_in[0];
    const float* k    = (const float*)d_in[1];
    const float* v    = (const float*)d_in[2];
    const void*  mask = d_in[3];
    const float* bias = (const float*)d_in[4];

    unsigned short* k2  = (unsigned short*)d_ws;                  // 16.78 MB
    unsigned short* v2  = k2 + (size_t)8388608;                   // 16.78 MB
    unsigned short* mb2 = k2 + (size_t)16777216;                  // 33.55 MB

    float* outp  = (float*)d_out;                                 // [B,H,L,D]
    float* attnp = outp + (size_t)8388608;                        // [B,H,L,S]

    convk2_kernel<<<4096, 256, 0, stream>>>(k, k2);
    convv2_kernel<<<4096, 256, 0, stream>>>(v, v2);
    fusemb2_kernel<<<8192, 256, 0, stream>>>(bias, mask, mb2);
    attn_main_kernel<<<8192, 256, 0, stream>>>(q, mb2, k2, v2, outp, attnp);
}

// Round 2
// 538.217 us; speedup vs baseline: 3.3261x; 3.3261x over previous
//
#include <hip/hip_runtime.h>
#include <hip/hip_bf16.h>
#include <stdint.h>

#define L_ 2048
#define S_ 2048
#define D_ 64

typedef float f32x4 __attribute__((ext_vector_type(4)));
typedef __bf16 bf16x8 __attribute__((ext_vector_type(8)));

__device__ __forceinline__ unsigned short f2b(float x) {
    return __builtin_bit_cast(unsigned short, (__bf16)x);
}
__device__ __forceinline__ float h2f(unsigned short u) {
    return (float)__builtin_bit_cast(_Float16, u);
}

// ============ prep 1: K fp32 -> K2 bf16 in per-(it,wave,lane) frag order ====
// K2 flat 16B units: t = ((((bh*8+it)*8+w)*2+nt)*2+ks)*64 + lan
// value e of unit = K[bh][s = it*256+w*32+nt*16+li][d = ks*32+g*8+e]
__global__ void convk2_kernel(const float* __restrict__ k, unsigned short* __restrict__ k2) {
    const int t = blockIdx.x * 256 + threadIdx.x;       // 1,048,576 total
    const int lan = t & 63, ks = (t >> 6) & 1, nt = (t >> 7) & 1;
    const int w = (t >> 8) & 7, it = (t >> 11) & 7, bh = t >> 14;
    const int li = lan & 15, g = lan >> 4;
    const int s  = it * 256 + w * 32 + nt * 16 + li;
    const int d0 = ks * 32 + g * 8;
    const float* src = k + ((size_t)bh * S_ + s) * D_ + d0;
    float4 a = *(const float4*)src;
    float4 b = *(const float4*)(src + 4);
    uint4 o;
    o.x = (unsigned)f2b(a.x) | ((unsigned)f2b(a.y) << 16);
    o.y = (unsigned)f2b(a.z) | ((unsigned)f2b(a.w) << 16);
    o.z = (unsigned)f2b(b.x) | ((unsigned)f2b(b.y) << 16);
    o.w = (unsigned)f2b(b.z) | ((unsigned)f2b(b.w) << 16);
    *(uint4*)(k2 + (size_t)t * 8) = o;
}

// ============ prep 2: V fp32 -> V2 bf16 frag order =========================
// V2 16B units: t = ((((bh*8+it)*8+w)*4+dt)*64) + lan
// value e = V[bh][s = it*256+w*32+g*8+e][d = dt*16+li]
__global__ void convv2_kernel(const float* __restrict__ v, unsigned short* __restrict__ v2) {
    const int t = blockIdx.x * 256 + threadIdx.x;       // 1,048,576 total
    const int lan = t & 63, dt = (t >> 6) & 3;
    const int w = (t >> 8) & 7, it = (t >> 11) & 7, bh = t >> 14;
    const int li = lan & 15, g = lan >> 4;
    const int s0 = it * 256 + w * 32 + g * 8;
    const int d  = dt * 16 + li;
    unsigned short o[8];
    #pragma unroll
    for (int e = 0; e < 8; ++e)
        o[e] = f2b(v[((size_t)bh * S_ + s0 + e) * D_ + d]);
    uint4 u;
    u.x = (unsigned)o[0] | ((unsigned)o[1] << 16);
    u.y = (unsigned)o[2] | ((unsigned)o[3] << 16);
    u.z = (unsigned)o[4] | ((unsigned)o[5] << 16);
    u.w = (unsigned)o[6] | ((unsigned)o[7] << 16);
    *(uint4*)(v2 + (size_t)t * 8) = u;
}

// ============ prep 3: bias+mask -> mb2 f16 in per-(it,thread) order ========
// mb2 16B units: t = (((b*128+lt)*8+it)*512) + tid512
// val[nt*4+j] = masked ? -60000 : bias[b][lt*16+g*4+j][it*256+w*32+nt*16+li]
__global__ void fusemb2_kernel(const float* __restrict__ bias, const void* __restrict__ maskp,
                               unsigned short* __restrict__ mb2) {
    const unsigned* mw = (const unsigned*)maskp;
    int is4 = 1;
    for (int i = 0; i < 64; ++i) {
        unsigned wv = mw[i];
        if (!(wv == 0u || wv == 1u || wv == 0x3F800000u)) { is4 = 0; break; }
    }
    const int t = blockIdx.x * 256 + threadIdx.x;       // 2,097,152 total
    const int tid = t & 511, it = (t >> 9) & 7, lt = (t >> 12) & 127, b = t >> 19;
    const int w = tid >> 6, lan = tid & 63, g = lan >> 4, li = lan & 15;
    const unsigned short NEG = __builtin_bit_cast(unsigned short, (_Float16)(-60000.0f));
    const int* maski = (const int*)maskp;
    const unsigned char* maskb = (const unsigned char*)maskp;
    unsigned short o[8];
    #pragma unroll
    for (int nt = 0; nt < 2; ++nt)
      #pragma unroll
      for (int j = 0; j < 4; ++j) {
          size_t idx = ((size_t)b * L_ + lt * 16 + g * 4 + j) * S_
                     + it * 256 + w * 32 + nt * 16 + li;
          int m = is4 ? (maski[idx] != 0) : (maskb[idx] != 0);
          o[nt * 4 + j] = m ? NEG
                            : __builtin_bit_cast(unsigned short, (_Float16)bias[idx]);
      }
    uint4 u;
    u.x = (unsigned)o[0] | ((unsigned)o[1] << 16);
    u.y = (unsigned)o[2] | ((unsigned)o[3] << 16);
    u.z = (unsigned)o[4] | ((unsigned)o[5] << 16);
    u.w = (unsigned)o[6] | ((unsigned)o[7] << 16);
    *(uint4*)(mb2 + (size_t)t * 8) = u;
}

// ============ main fused attention =========================================
// Round-0 structure (1024 WGs = (b, 128 l-tiles, 2 h-groups), 512 thr,
// single-pass softmax, scores held in regs) + ONE change: the block's mb2
// slice for its 0..3 (32 KB) is loaded into LDS once and reused across all
// 8 heads. This removes the dominant L2-thrash re-fetch (mb2 was re-read
// ~once per head: ~270 MB of the 566 MB FETCH_SIZE), and halves the
// streamed mb2 L2 footprint (32 slices x 32.5 KB ~= 1 MB/XCD) so the
// remaining half stays L2-resident across heads. LDS 32->64 KB; residency
// still 2 blocks/CU (register-limited), occupancy unchanged.
__launch_bounds__(512, 4)
__global__ void attn_main_kernel(const float* __restrict__ q,
                                 const unsigned short* __restrict__ mb2,
                                 const unsigned short* __restrict__ k2,
                                 const unsigned short* __restrict__ v2,
                                 float* __restrict__ outp,
                                 float* __restrict__ attnp)
{
    __shared__ __align__(16) char lds[65536];
    float* outred = (float*)lds;                 // [8][16][64] f32 (post-PV)
    float* redbuf = (float*)(lds + 10240);       // [8][16]  (softmax, overlaid)
    float* rowred = (float*)(lds + 10752);       // [16]
    unsigned short* mbl = (unsigned short*)(lds + 32768); // mb2 its 0..3, 32 KB
    const int tid = threadIdx.x;
    const int w = tid >> 6, lan = tid & 63, g = lan >> 4, li = lan & 15;
    char* pbuf = lds + w * 1280;                 // per-wave P tile [16][80B] (PV)

    // bijective XCD chunking: XCD x gets 128 consecutive c; hg pairs adjacent
    const int c  = ((blockIdx.x & 7) << 7) | (blockIdx.x >> 3);
    const int b  = c >> 8;
    const int lt = (c & 255) >> 1;
    const int hg = c & 1;
    const int l0 = lt * 16;

    const unsigned short* mbbase = mb2 + ((size_t)(b * 128 + lt) * 8) * 4096 + (size_t)tid * 8;
    const f32x4 vzero = {0.f, 0.f, 0.f, 0.f};

    // ---- one-time: mb2 its 0..3 -> LDS (linear per-tid layout) ----
    #pragma unroll
    for (int it = 0; it < 4; ++it) {
        uint4 u = *(const uint4*)(mbbase + it * 4096);
        *(uint4*)(mbl + (size_t)(it * 512 + tid) * 8) = u;
    }
    __syncthreads();

    #pragma unroll 1
    for (int hh = 0; hh < 8; ++hh) {
        const int bh = (b << 4) + (hg << 3) + hh;
        const unsigned short* kbase = k2 + (size_t)bh * 131072 + w * 2048 + (size_t)lan * 8;
        const unsigned short* vbase = v2 + (size_t)bh * 131072 + w * 2048 + (size_t)lan * 8;

        // ---- Q fragments ----
        bf16x8 qf[2];
        #pragma unroll
        for (int ks = 0; ks < 2; ++ks) {
            const float* qp = q + ((size_t)bh * L_ + (l0 + li)) * D_ + ks * 32 + g * 8;
            float4 x = *(const float4*)qp;
            float4 y = *(const float4*)(qp + 4);
            bf16x8 f;
            f[0]=(__bf16)x.x; f[1]=(__bf16)x.y; f[2]=(__bf16)x.z; f[3]=(__bf16)x.w;
            f[4]=(__bf16)y.x; f[5]=(__bf16)y.y; f[6]=(__bf16)y.z; f[7]=(__bf16)y.w;
            qf[ks] = f;
        }

        f32x4 acc[8][2];
        #pragma unroll
        for (int it = 0; it < 8; ++it) { acc[it][0] = vzero; acc[it][1] = vzero; }
        float vmax[4] = {-3.0e38f, -3.0e38f, -3.0e38f, -3.0e38f};

        // ================= score phase (barrier-free) =================
        #pragma unroll
        for (int it = 0; it < 8; ++it) {
            const unsigned short* kit = kbase + it * 16384;
            uint4 f00 = *(const uint4*)(kit);            // nt0 ks0
            uint4 f01 = *(const uint4*)(kit + 512);      // nt0 ks1
            uint4 f10 = *(const uint4*)(kit + 1024);     // nt1 ks0
            uint4 f11 = *(const uint4*)(kit + 1536);     // nt1 ks1
            uint4 mp;
            if (it < 4)
                mp = *(const uint4*)(mbl + (size_t)(it * 512 + tid) * 8);     // LDS half
            else
                mp = *(const uint4*)(mbbase + it * 4096);                     // L2 stream
            acc[it][0] = __builtin_amdgcn_mfma_f32_16x16x32_bf16(
                qf[0], __builtin_bit_cast(bf16x8, f00), acc[it][0], 0, 0, 0);
            acc[it][0] = __builtin_amdgcn_mfma_f32_16x16x32_bf16(
                qf[1], __builtin_bit_cast(bf16x8, f01), acc[it][0], 0, 0, 0);
            acc[it][1] = __builtin_amdgcn_mfma_f32_16x16x32_bf16(
                qf[0], __builtin_bit_cast(bf16x8, f10), acc[it][1], 0, 0, 0);
            acc[it][1] = __builtin_amdgcn_mfma_f32_16x16x32_bf16(
                qf[1], __builtin_bit_cast(bf16x8, f11), acc[it][1], 0, 0, 0);
            float mbv[2][4];
            mbv[0][0] = h2f((unsigned short)(mp.x & 0xffff));
            mbv[0][1] = h2f((unsigned short)(mp.x >> 16));
            mbv[0][2] = h2f((unsigned short)(mp.y & 0xffff));
            mbv[0][3] = h2f((unsigned short)(mp.y >> 16));
            mbv[1][0] = h2f((unsigned short)(mp.z & 0xffff));
            mbv[1][1] = h2f((unsigned short)(mp.z >> 16));
            mbv[1][2] = h2f((unsigned short)(mp.w & 0xffff));
            mbv[1][3] = h2f((unsigned short)(mp.w >> 16));
            #pragma unroll
            for (int nt = 0; nt < 2; ++nt)
              #pragma unroll
              for (int j = 0; j < 4; ++j) {
                  float s = fmaf(acc[it][nt][j], 0.125f, mbv[nt][j]);
                  acc[it][nt][j] = s;
                  vmax[j] = fmaxf(vmax[j], s);
              }
        }

        // ================= softmax (16 rows, 2 barriers) =================
        #pragma unroll
        for (int j = 0; j < 4; ++j) {
            float m = vmax[j];
            m = fmaxf(m, __shfl_xor(m, 1));
            m = fmaxf(m, __shfl_xor(m, 2));
            m = fmaxf(m, __shfl_xor(m, 4));
            m = fmaxf(m, __shfl_xor(m, 8));
            vmax[j] = m;
        }
        if (li == 0) {
            #pragma unroll
            for (int j = 0; j < 4; ++j) redbuf[w * 16 + g * 4 + j] = vmax[j];
        }
        __syncthreads();
        if (tid < 16) {
            float m = -3.0e38f;
            #pragma unroll
            for (int ww = 0; ww < 8; ++ww) m = fmaxf(m, redbuf[ww * 16 + tid]);
            rowred[tid] = m;
        }
        __syncthreads();
        float rmax[4];
        #pragma unroll
        for (int j = 0; j < 4; ++j) rmax[j] = rowred[g * 4 + j];

        float vs[4] = {0.f, 0.f, 0.f, 0.f};
        #pragma unroll
        for (int it = 0; it < 8; ++it)
          #pragma unroll
          for (int nt = 0; nt < 2; ++nt)
            #pragma unroll
            for (int j = 0; j < 4; ++j) {
                float pp = __expf(acc[it][nt][j] - rmax[j]);
                acc[it][nt][j] = pp;
                vs[j] += pp;
            }
        #pragma unroll
        for (int j = 0; j < 4; ++j) {
            float s = vs[j];
            s += __shfl_xor(s, 1);
            s += __shfl_xor(s, 2);
            s += __shfl_xor(s, 4);
            s += __shfl_xor(s, 8);
            vs[j] = s;
        }
        if (li == 0) {
            #pragma unroll
            for (int j = 0; j < 4; ++j) redbuf[w * 16 + g * 4 + j] = vs[j];
        }
        __syncthreads();
        if (tid < 16) {
            float s = 0.f;
            #pragma unroll
            for (int ww = 0; ww < 8; ++ww) s += redbuf[ww * 16 + tid];
            rowred[tid] = s;
        }
        __syncthreads();
        float rinv[4];
        #pragma unroll
        for (int j = 0; j < 4; ++j) rinv[j] = 1.0f / rowred[g * 4 + j];

        // ========== PV phase + attn stores (barrier-free, per-wave) ==========
        f32x4 oacc[4];
        #pragma unroll
        for (int dt = 0; dt < 4; ++dt) oacc[dt] = vzero;
        float* attnw = attnp + (size_t)bh * L_ * S_ + (size_t)l0 * S_;

        #pragma unroll
        for (int it = 0; it < 8; ++it) {
            const unsigned short* vit = vbase + it * 16384;
            float a[2][4];
            #pragma unroll
            for (int nt = 0; nt < 2; ++nt)
              #pragma unroll
              for (int j = 0; j < 4; ++j) a[nt][j] = acc[it][nt][j] * rinv[j];
            // nontemporal attn stores; j-outer/nt-inner pairs 128B lines
            #pragma unroll
            for (int j = 0; j < 4; ++j)
              #pragma unroll
              for (int nt = 0; nt < 2; ++nt)
                  __builtin_nontemporal_store(a[nt][j],
                      attnw + (size_t)(g * 4 + j) * S_ + it * 256 + w * 32 + nt * 16 + li);
            // P -> per-wave LDS (wave-local transpose bounce; same-wave ds
            // ordering via lgkmcnt, no barrier)
            #pragma unroll
            for (int nt = 0; nt < 2; ++nt)
              #pragma unroll
              for (int j = 0; j < 4; ++j)
                  *(unsigned short*)(pbuf + (g * 4 + j) * 80 + (nt * 16 + li) * 2)
                      = f2b(a[nt][j]);
            bf16x8 pf = *(const bf16x8*)(pbuf + li * 80 + g * 16);
            #pragma unroll
            for (int dt = 0; dt < 4; ++dt) {
                uint4 vd = *(const uint4*)(vit + dt * 512);
                oacc[dt] = __builtin_amdgcn_mfma_f32_16x16x32_bf16(
                    pf, __builtin_bit_cast(bf16x8, vd), oacc[dt], 0, 0, 0);
            }
        }

        // ================= cross-wave out reduction =================
        __syncthreads();                         // PV done (pbuf -> outred reuse)
        #pragma unroll
        for (int dt = 0; dt < 4; ++dt)
          #pragma unroll
          for (int j = 0; j < 4; ++j)
              outred[(w * 16 + g * 4 + j) * 64 + dt * 16 + li] = oacc[dt][j];
        __syncthreads();
        if (tid < 256) {
            int r = tid >> 4, c4 = (tid & 15) << 2;
            f32x4 ssum = vzero;
            #pragma unroll
            for (int ww = 0; ww < 8; ++ww)
                ssum += *(const f32x4*)(outred + (ww * 16 + r) * 64 + c4);
            __builtin_nontemporal_store(ssum,
                (f32x4*)(outp + ((size_t)bh * L_ + (l0 + r)) * D_ + c4));
        }
        __syncthreads();                         // protect outred/redbuf reuse
    }
}

extern "C" void kernel_launch(void* const* d_in, const int* in_sizes, int n_in,
                              void* d_out, int out_size, void* d_ws, size_t ws_size,
                              hipStream_t stream) {
    const float* q    = (const float*)d_in[0];
    const float* k    = (const float*)d_in[1];
    const float* v    = (const float*)d_in[2];
    const void*  mask = d_in[3];
    const float* bias = (const float*)d_in[4];

    unsigned short* k2  = (unsigned short*)d_ws;                  // 16.78 MB
    unsigned short* v2  = k2 + (size_t)8388608;                   // 16.78 MB
    unsigned short* mb2 = k2 + (size_t)16777216;                  // 33.55 MB

    float* outp  = (float*)d_out;                                 // [B,H,L,D]
    float* attnp = outp + (size_t)8388608;                        // [B,H,L,S]

    convk2_kernel<<<4096, 256, 0, stream>>>(k, k2);
    convv2_kernel<<<4096, 256, 0, stream>>>(v, v2);
    fusemb2_kernel<<<8192, 256, 0, stream>>>(bias, mask, mb2);
    attn_main_kernel<<<1024, 512, 0, stream>>>(q, mb2, k2, v2, outp, attnp);
}